// Round 2
// baseline (324.058 us; speedup 1.0000x reference)
//
#include <hip/hip_runtime.h>

#define N_NODES 200000
#define N_EDGES 600000
#define F_IN 165
#define F_HID 128
#define KP 200  // LDS/global row stride for bf16 tiles (ushorts); 400B stride: 16B-aligned, bank-stride 4 -> 2-way max

typedef short short8 __attribute__((ext_vector_type(8)));
typedef float f32x4 __attribute__((ext_vector_type(4)));

__device__ __forceinline__ unsigned short f2bf(float f) {
  union { float f; unsigned int u; } v; v.f = f;
  unsigned int u = v.u;
  return (unsigned short)((u + 0x7FFFu + ((u >> 16) & 1u)) >> 16);  // RNE
}

// ---- zero scratch counters (NOT hipMemsetAsync: must be a graph-replayed node) ----
__global__ void k_zero(int* __restrict__ cnt, int* __restrict__ fill) {
  int i = blockIdx.x * 256 + threadIdx.x;
  if (i < N_NODES) { cnt[i] = 0; fill[i] = 0; }
}

// ---- CSR build ----
__global__ void k_count(const int* __restrict__ ei, int* __restrict__ cnt) {
  int e = blockIdx.x * 256 + threadIdx.x;
  if (e < N_EDGES) atomicAdd(&cnt[ei[N_EDGES + e]], 1);
}

__global__ void k_scan1(const int* __restrict__ cnt, int* __restrict__ rowptr, int* __restrict__ bsum) {
  __shared__ int sd[256];
  int t = threadIdx.x;
  int idx = blockIdx.x * 256 + t;
  int v = (idx < N_NODES) ? cnt[idx] : 0;
  sd[t] = v; __syncthreads();
  #pragma unroll
  for (int off = 1; off < 256; off <<= 1) {
    int u = (t >= off) ? sd[t - off] : 0;
    __syncthreads();
    sd[t] += u;
    __syncthreads();
  }
  if (idx < N_NODES) rowptr[idx] = sd[t] - v;  // exclusive within block
  if (t == 255) bsum[blockIdx.x] = sd[t];
}

__global__ void k_scan2(int* __restrict__ bsum, int nb) {
  __shared__ int sd[1024];
  int t = threadIdx.x;
  int v = (t < nb) ? bsum[t] : 0;
  sd[t] = v; __syncthreads();
  for (int off = 1; off < 1024; off <<= 1) {
    int u = (t >= off) ? sd[t - off] : 0;
    __syncthreads();
    sd[t] += u;
    __syncthreads();
  }
  if (t < nb) bsum[t] = sd[t] - v;  // exclusive block offsets
}

__global__ void k_scan3(const int* __restrict__ cnt, const int* __restrict__ bsum,
                        int* __restrict__ rowptr, float* __restrict__ dinv) {
  int idx = blockIdx.x * 256 + threadIdx.x;
  if (idx < N_NODES) {
    rowptr[idx] += bsum[blockIdx.x];
    dinv[idx] = rsqrtf((float)(cnt[idx] + 1));  // deg = in-degree + self-loop >= 1
  }
  if (idx == 0) rowptr[N_NODES] = N_EDGES;
}

__global__ void k_fill(const int* __restrict__ ei, const int* __restrict__ rowptr,
                       int* __restrict__ fill, int* __restrict__ srcl) {
  int e = blockIdx.x * 256 + threadIdx.x;
  if (e < N_EDGES) {
    int d = ei[N_EDGES + e];
    int s = ei[e];
    int slot = atomicAdd(&fill[d], 1);
    srcl[rowptr[d] + slot] = s;
  }
}

// ---- W1^T -> bf16, padded [128][KP], zeros beyond k=165 ----
__global__ void k_wt(const float* __restrict__ W1, unsigned short* __restrict__ wt) {
  int idx = blockIdx.x * 256 + threadIdx.x;
  if (idx < F_HID * KP) {
    int c = idx / KP, k = idx - c * KP;
    wt[idx] = (k < F_IN) ? f2bf(W1[k * F_HID + c]) : (unsigned short)0;
  }
}

// ---- GEMM1: h = X @ W1  (bf16 MFMA, fp32 accum). Block: 32 rows x 128 cols. ----
__global__ __launch_bounds__(256) void k_gemm1(const float* __restrict__ x,
                                               const unsigned short* __restrict__ wt,
                                               float* __restrict__ h) {
  __shared__ unsigned short As[32 * KP];   // 12.8 KB
  __shared__ unsigned short Bs[F_HID * KP]; // 51.2 KB  (total 64000 B <= 64 KB)
  int tid = threadIdx.x;

  // stage W^T (flat copy, already padded bf16 in global)
  const uint4* wt4 = (const uint4*)wt;
  uint4* Bs4 = (uint4*)Bs;
  #pragma unroll 4
  for (int j = tid; j < F_HID * KP / 8; j += 256) Bs4[j] = wt4[j];

  // stage A: 32 contiguous rows of x, fp32 -> bf16, padded to KP with zeros
  long r0 = (long)blockIdx.x * 32;
  const float4* x4 = (const float4*)(x + r0 * F_IN);  // block chunk is 16B-aligned (32*165*4 = 21120)
  for (int j = tid; j < 32 * F_IN / 4; j += 256) {
    float4 v = x4[j];
    int e = 4 * j;
    #pragma unroll
    for (int u = 0; u < 4; ++u) {
      int ee = e + u;
      int r = ee / F_IN, c = ee - r * F_IN;
      As[r * KP + c] = f2bf((&v.x)[u]);
    }
  }
  for (int j = tid; j < 32 * (KP - F_IN); j += 256) {
    int r = j / (KP - F_IN), c = F_IN + (j - r * (KP - F_IN));
    As[r * KP + c] = 0;
  }
  __syncthreads();

  int lane = tid & 63;
  int w = tid >> 6;
  int rg = w & 1;   // row group (16 rows)
  int ch = w >> 1;  // col half (64 cols)
  int arow = rg * 16 + (lane & 15);
  int kg = (lane >> 4) * 8;  // same k-permutation for A and B fragments -> dot product invariant
  f32x4 acc[4];
  #pragma unroll
  for (int i = 0; i < 4; ++i) acc[i] = (f32x4){0.f, 0.f, 0.f, 0.f};
  #pragma unroll
  for (int ks = 0; ks < 6; ++ks) {  // K padded to 192, zeros beyond 165
    short8 af = *(const short8*)(&As[arow * KP + ks * 32 + kg]);
    #pragma unroll
    for (int cb = 0; cb < 4; ++cb) {
      int col = (ch * 4 + cb) * 16 + (lane & 15);
      short8 bf = *(const short8*)(&Bs[col * KP + ks * 32 + kg]);
      acc[cb] = __builtin_amdgcn_mfma_f32_16x16x32_bf16(af, bf, acc[cb], 0, 0, 0);
    }
  }
  // C/D layout (HW-verified): col = lane&15, row = (lane>>4)*4 + reg
  long orow = r0 + rg * 16 + (lane >> 4) * 4;
  int ocol = lane & 15;
  #pragma unroll
  for (int cb = 0; cb < 4; ++cb) {
    #pragma unroll
    for (int j = 0; j < 4; ++j) {
      h[(orow + j) * F_HID + (ch * 4 + cb) * 16 + ocol] = acc[cb][j];
    }
  }
}

// ---- fused: agg1 (gather) + bias + relu + GEMM2 (128->2 reduction) ----
__global__ __launch_bounds__(256) void k_agg1(const float* __restrict__ h, const float* __restrict__ dinv,
                                              const int* __restrict__ rowptr, const int* __restrict__ srcl,
                                              const float* __restrict__ b1, const float* __restrict__ W2,
                                              float* __restrict__ h2) {
  __shared__ float red[4][2];
  int tid = threadIdx.x;
  int local = tid >> 7;   // 2 nodes per block
  int f = tid & 127;
  int d = blockIdx.x * 2 + local;
  float dd = dinv[d];
  float acc = h[(long)d * F_HID + f] * dd * dd;  // self-loop: norm = 1/deg
  int i1 = rowptr[d + 1];
  for (int i = rowptr[d]; i < i1; ++i) {
    int s = srcl[i];
    acc += h[(long)s * F_HID + f] * (dinv[s] * dd);
  }
  float a1 = acc + b1[f];
  a1 = a1 > 0.f ? a1 : 0.f;
  float p0 = a1 * W2[2 * f];
  float p1 = a1 * W2[2 * f + 1];
  #pragma unroll
  for (int off = 32; off > 0; off >>= 1) {
    p0 += __shfl_down(p0, off);
    p1 += __shfl_down(p1, off);
  }
  int wv = tid >> 6;
  if ((tid & 63) == 0) { red[wv][0] = p0; red[wv][1] = p1; }
  __syncthreads();
  if ((tid & 127) == 0) {
    int w0 = local * 2;
    h2[2 * d]     = red[w0][0] + red[w0 + 1][0];
    h2[2 * d + 1] = red[w0][1] + red[w0 + 1][1];
  }
}

// ---- agg2 over 2 features + bias ----
__global__ void k_agg2(const float* __restrict__ h2, const float* __restrict__ dinv,
                       const int* __restrict__ rowptr, const int* __restrict__ srcl,
                       const float* __restrict__ b2, float* __restrict__ out) {
  int d = blockIdx.x * 256 + threadIdx.x;
  if (d >= N_NODES) return;
  float dd = dinv[d];
  const float2* h2v = (const float2*)h2;
  float2 hv = h2v[d];
  float o0 = hv.x * dd * dd;
  float o1 = hv.y * dd * dd;
  int i1 = rowptr[d + 1];
  for (int i = rowptr[d]; i < i1; ++i) {
    int s = srcl[i];
    float2 hs = h2v[s];
    float nm = dinv[s] * dd;
    o0 += hs.x * nm;
    o1 += hs.y * nm;
  }
  float2* ov = (float2*)out;
  ov[d] = make_float2(o0 + b2[0], o1 + b2[1]);
}

extern "C" void kernel_launch(void* const* d_in, const int* in_sizes, int n_in,
                              void* d_out, int out_size, void* d_ws, size_t ws_size,
                              hipStream_t stream) {
  const float* x  = (const float*)d_in[0];
  const int*   ei = (const int*)d_in[1];
  const float* W1 = (const float*)d_in[2];
  const float* b1 = (const float*)d_in[3];
  const float* W2 = (const float*)d_in[4];
  const float* b2 = (const float*)d_in[5];
  float* out = (float*)d_out;

  char* p = (char*)d_ws;
  size_t off = 0;
  auto take = [&](size_t bytes) -> void* {
    void* r = p + off;
    off += (bytes + 255) & ~(size_t)255;
    return r;
  };
  float*          h      = (float*)take((size_t)N_NODES * F_HID * 4);  // 102.4 MB
  unsigned short* wt     = (unsigned short*)take((size_t)F_HID * KP * 2);
  float*          h2     = (float*)take((size_t)N_NODES * 2 * 4);
  int*            cnt    = (int*)take((size_t)N_NODES * 4);
  int*            fill   = (int*)take((size_t)N_NODES * 4);
  int*            rowptr = (int*)take(((size_t)N_NODES + 1) * 4);
  int*            srcl   = (int*)take((size_t)N_EDGES * 4);
  float*          dinv   = (float*)take((size_t)N_NODES * 4);
  int*            bsum   = (int*)take(4096);
  (void)ws_size; (void)in_sizes; (void)n_in; (void)out_size;

  int nbE = (N_EDGES + 255) / 256;
  int nbN = (N_NODES + 255) / 256;
  k_zero<<<nbN, 256, 0, stream>>>(cnt, fill);
  k_count<<<nbE, 256, 0, stream>>>(ei, cnt);
  k_scan1<<<nbN, 256, 0, stream>>>(cnt, rowptr, bsum);
  k_scan2<<<1, 1024, 0, stream>>>(bsum, nbN);
  k_scan3<<<nbN, 256, 0, stream>>>(cnt, bsum, rowptr, dinv);
  k_fill<<<nbE, 256, 0, stream>>>(ei, rowptr, fill, srcl);
  k_wt<<<(F_HID * KP + 255) / 256, 256, 0, stream>>>(W1, wt);
  k_gemm1<<<N_NODES / 32, 256, 0, stream>>>(x, wt, h);
  k_agg1<<<N_NODES / 2, 256, 0, stream>>>(h, dinv, rowptr, srcl, b1, W2, h2);
  k_agg2<<<nbN, 256, 0, stream>>>(h2, dinv, rowptr, srcl, b2, out);
}

// Round 3
// 213.001 us; speedup vs baseline: 1.5214x; 1.5214x over previous
//
#include <hip/hip_runtime.h>

#define N_NODES 200000
#define N_EDGES 600000
#define F_IN 165
#define F_HID 128
#define KP 200  // LDS row stride for bf16 tiles (ushorts)

typedef short short8 __attribute__((ext_vector_type(8)));
typedef float f32x4 __attribute__((ext_vector_type(4)));

__device__ __forceinline__ unsigned short f2bf(float f) {
  union { float f; unsigned int u; } v; v.f = f;
  unsigned int u = v.u;
  return (unsigned short)((u + 0x7FFFu + ((u >> 16) & 1u)) >> 16);  // RNE
}
__device__ __forceinline__ float bflo(unsigned int v) {
  union { unsigned int u; float f; } x; x.u = v << 16; return x.f;
}
__device__ __forceinline__ float bfhi(unsigned int v) {
  union { unsigned int u; float f; } x; x.u = v & 0xffff0000u; return x.f;
}

// ---- zero scratch counters (graph-replayed node, not hipMemsetAsync) ----
__global__ void k_zero(int* __restrict__ cnt) {
  int i = blockIdx.x * 256 + threadIdx.x;
  if (i < N_NODES) cnt[i] = 0;
}

// ---- CSR build ----
__global__ void k_count(const int* __restrict__ ei, int* __restrict__ cnt) {
  int e = blockIdx.x * 256 + threadIdx.x;
  if (e < N_EDGES) atomicAdd(&cnt[ei[N_EDGES + e]], 1);
}

__global__ void k_scan1(const int* __restrict__ cnt, int* __restrict__ rowptr, int* __restrict__ bsum) {
  __shared__ int sd[256];
  int t = threadIdx.x;
  int idx = blockIdx.x * 256 + t;
  int v = (idx < N_NODES) ? cnt[idx] : 0;
  sd[t] = v; __syncthreads();
  #pragma unroll
  for (int off = 1; off < 256; off <<= 1) {
    int u = (t >= off) ? sd[t - off] : 0;
    __syncthreads();
    sd[t] += u;
    __syncthreads();
  }
  if (idx < N_NODES) rowptr[idx] = sd[t] - v;  // exclusive within block
  if (t == 255) bsum[blockIdx.x] = sd[t];
}

__global__ void k_scan2(int* __restrict__ bsum, int nb) {
  __shared__ int sd[1024];
  int t = threadIdx.x;
  int v = (t < nb) ? bsum[t] : 0;
  sd[t] = v; __syncthreads();
  for (int off = 1; off < 1024; off <<= 1) {
    int u = (t >= off) ? sd[t - off] : 0;
    __syncthreads();
    sd[t] += u;
    __syncthreads();
  }
  if (t < nb) bsum[t] = sd[t] - v;  // exclusive block offsets
}

__global__ void k_scan3(const int* __restrict__ cnt, const int* __restrict__ bsum,
                        int* __restrict__ rowptr, int* __restrict__ fill, float* __restrict__ dinv) {
  int idx = blockIdx.x * 256 + threadIdx.x;
  if (idx < N_NODES) {
    int rp = rowptr[idx] + bsum[blockIdx.x];
    rowptr[idx] = rp;
    fill[idx] = rp;  // mutable cursor for k_fill
    dinv[idx] = rsqrtf((float)(cnt[idx] + 1));  // deg = in-degree + self-loop >= 1
  }
  if (idx == 0) rowptr[N_NODES] = N_EDGES;
}

__global__ void k_fill(const int* __restrict__ ei, int* __restrict__ fill, int* __restrict__ srcl) {
  int e = blockIdx.x * 256 + threadIdx.x;
  if (e < N_EDGES) {
    int d = ei[N_EDGES + e];
    int s = ei[e];
    int slot = atomicAdd(&fill[d], 1);
    srcl[slot] = s;
  }
}

// ---- W1^T -> bf16, padded [128][KP], zeros beyond k=165 ----
__global__ void k_wt(const float* __restrict__ W1, unsigned short* __restrict__ wt) {
  int idx = blockIdx.x * 256 + threadIdx.x;
  if (idx < F_HID * KP) {
    int c = idx / KP, k = idx - c * KP;
    wt[idx] = (k < F_IN) ? f2bf(W1[k * F_HID + c]) : (unsigned short)0;
  }
}

// ---- GEMM1: h = X @ W1 (bf16 MFMA, fp32 accum); epilogue scales by dinv[row], stores bf16 ----
__global__ __launch_bounds__(256) void k_gemm1(const float* __restrict__ x,
                                               const unsigned short* __restrict__ wt,
                                               const float* __restrict__ dinv,
                                               unsigned short* __restrict__ h16) {
  __shared__ unsigned short As[32 * KP];    // 12.8 KB
  __shared__ unsigned short Bs[F_HID * KP]; // 51.2 KB
  int tid = threadIdx.x;

  const uint4* wt4 = (const uint4*)wt;
  uint4* Bs4 = (uint4*)Bs;
  #pragma unroll 4
  for (int j = tid; j < F_HID * KP / 8; j += 256) Bs4[j] = wt4[j];

  long r0 = (long)blockIdx.x * 32;
  const float4* x4 = (const float4*)(x + r0 * F_IN);  // 32*165*4 = 21120B chunks, 16B-aligned
  for (int j = tid; j < 32 * F_IN / 4; j += 256) {
    float4 v = x4[j];
    int e = 4 * j;
    #pragma unroll
    for (int u = 0; u < 4; ++u) {
      int ee = e + u;
      int r = ee / F_IN, c = ee - r * F_IN;
      As[r * KP + c] = f2bf((&v.x)[u]);
    }
  }
  for (int j = tid; j < 32 * (KP - F_IN); j += 256) {
    int r = j / (KP - F_IN), c = F_IN + (j - r * (KP - F_IN));
    As[r * KP + c] = 0;
  }
  __syncthreads();

  int lane = tid & 63;
  int w = tid >> 6;
  int rg = w & 1;   // row group (16 rows)
  int ch = w >> 1;  // col half (64 cols)
  int arow = rg * 16 + (lane & 15);
  int kg = (lane >> 4) * 8;  // same k-permutation for A and B fragments
  f32x4 acc[4];
  #pragma unroll
  for (int i = 0; i < 4; ++i) acc[i] = (f32x4){0.f, 0.f, 0.f, 0.f};
  #pragma unroll
  for (int ks = 0; ks < 6; ++ks) {  // K padded to 192, zeros beyond 165
    short8 af = *(const short8*)(&As[arow * KP + ks * 32 + kg]);
    #pragma unroll
    for (int cb = 0; cb < 4; ++cb) {
      int col = (ch * 4 + cb) * 16 + (lane & 15);
      short8 bf = *(const short8*)(&Bs[col * KP + ks * 32 + kg]);
      acc[cb] = __builtin_amdgcn_mfma_f32_16x16x32_bf16(af, bf, acc[cb], 0, 0, 0);
    }
  }
  // C/D layout: col = lane&15, row = (lane>>4)*4 + reg
  long orow = r0 + rg * 16 + (lane >> 4) * 4;
  int ocol = lane & 15;
  float dv[4];
  #pragma unroll
  for (int j = 0; j < 4; ++j) dv[j] = dinv[orow + j];
  #pragma unroll
  for (int cb = 0; cb < 4; ++cb) {
    #pragma unroll
    for (int j = 0; j < 4; ++j) {
      h16[(orow + j) * F_HID + (ch * 4 + cb) * 16 + ocol] = f2bf(acc[cb][j] * dv[j]);
    }
  }
}

// ---- fused: agg1 (gather, 4-wide) + bias + relu + GEMM2 (128->2) ; output pre-scaled by dinv ----
__global__ __launch_bounds__(256) void k_agg1(const unsigned int* __restrict__ H,  // bf16x2 rows, 64 uints/node
                                              const float* __restrict__ dinv,
                                              const int* __restrict__ rowptr, const int* __restrict__ srcl,
                                              const float* __restrict__ b1, const float* __restrict__ W2,
                                              float* __restrict__ h2s) {
  int tid = threadIdx.x;
  int local = tid >> 6;
  int lane = tid & 63;
  int d = blockIdx.x * 4 + local;  // grid exact: 50000*4 = 200000

  unsigned int v = H[(long)d * 64 + lane];  // self (already dinv[d]-scaled)
  float acc0 = bflo(v), acc1 = bfhi(v);
  int r0 = rowptr[d], r1 = rowptr[d + 1];
  int n = r1 - r0;
  for (int b = 0; b < n; b += 4) {
    int i0 = r0 + b;
    bool m1 = b + 1 < n, m2 = b + 2 < n, m3 = b + 3 < n;
    int s0 = srcl[i0];
    int s1 = m1 ? srcl[i0 + 1] : s0;
    int s2 = m2 ? srcl[i0 + 2] : s0;
    int s3 = m3 ? srcl[i0 + 3] : s0;
    unsigned int v0 = H[(long)s0 * 64 + lane];
    unsigned int v1 = H[(long)s1 * 64 + lane];
    unsigned int v2 = H[(long)s2 * 64 + lane];
    unsigned int v3 = H[(long)s3 * 64 + lane];
    acc0 += bflo(v0);                      acc1 += bfhi(v0);
    acc0 = fmaf(m1 ? 1.f : 0.f, bflo(v1), acc0); acc1 = fmaf(m1 ? 1.f : 0.f, bfhi(v1), acc1);
    acc0 = fmaf(m2 ? 1.f : 0.f, bflo(v2), acc0); acc1 = fmaf(m2 ? 1.f : 0.f, bfhi(v2), acc1);
    acc0 = fmaf(m3 ? 1.f : 0.f, bflo(v3), acc0); acc1 = fmaf(m3 ? 1.f : 0.f, bfhi(v3), acc1);
  }
  float dd = dinv[d];
  float2 bb = ((const float2*)b1)[lane];
  float a0 = fmaxf(fmaf(acc0, dd, bb.x), 0.f);
  float a1 = fmaxf(fmaf(acc1, dd, bb.y), 0.f);
  float4 w2 = ((const float4*)W2)[lane];  // W2[2*lane][0..1], W2[2*lane+1][0..1]
  float p0 = a0 * w2.x + a1 * w2.z;
  float p1 = a0 * w2.y + a1 * w2.w;
  #pragma unroll
  for (int off = 32; off > 0; off >>= 1) {
    p0 += __shfl_down(p0, off);
    p1 += __shfl_down(p1, off);
  }
  if (lane == 0) ((float2*)h2s)[d] = make_float2(p0 * dd, p1 * dd);
}

// ---- agg2 over 2 features + bias (h2s pre-scaled by dinv) ----
__global__ void k_agg2(const float* __restrict__ h2s, const float* __restrict__ dinv,
                       const int* __restrict__ rowptr, const int* __restrict__ srcl,
                       const float* __restrict__ b2, float* __restrict__ out) {
  int d = blockIdx.x * 256 + threadIdx.x;
  if (d >= N_NODES) return;
  const float2* G = (const float2*)h2s;
  float2 g = G[d];
  float o0 = g.x, o1 = g.y;
  int r0 = rowptr[d], r1 = rowptr[d + 1];
  int n = r1 - r0;
  for (int b = 0; b < n; b += 4) {
    int i0 = r0 + b;
    bool m1 = b + 1 < n, m2 = b + 2 < n, m3 = b + 3 < n;
    int s0 = srcl[i0];
    int s1 = m1 ? srcl[i0 + 1] : s0;
    int s2 = m2 ? srcl[i0 + 2] : s0;
    int s3 = m3 ? srcl[i0 + 3] : s0;
    float2 g0 = G[s0], g1 = G[s1], g2 = G[s2], g3 = G[s3];
    o0 += g0.x;                   o1 += g0.y;
    o0 = fmaf(m1 ? 1.f : 0.f, g1.x, o0); o1 = fmaf(m1 ? 1.f : 0.f, g1.y, o1);
    o0 = fmaf(m2 ? 1.f : 0.f, g2.x, o0); o1 = fmaf(m2 ? 1.f : 0.f, g2.y, o1);
    o0 = fmaf(m3 ? 1.f : 0.f, g3.x, o0); o1 = fmaf(m3 ? 1.f : 0.f, g3.y, o1);
  }
  float dd = dinv[d];
  ((float2*)out)[d] = make_float2(fmaf(o0, dd, b2[0]), fmaf(o1, dd, b2[1]));
}

extern "C" void kernel_launch(void* const* d_in, const int* in_sizes, int n_in,
                              void* d_out, int out_size, void* d_ws, size_t ws_size,
                              hipStream_t stream) {
  const float* x  = (const float*)d_in[0];
  const int*   ei = (const int*)d_in[1];
  const float* W1 = (const float*)d_in[2];
  const float* b1 = (const float*)d_in[3];
  const float* W2 = (const float*)d_in[4];
  const float* b2 = (const float*)d_in[5];
  float* out = (float*)d_out;

  char* p = (char*)d_ws;
  size_t off = 0;
  auto take = [&](size_t bytes) -> void* {
    void* r = p + off;
    off += (bytes + 255) & ~(size_t)255;
    return r;
  };
  unsigned short* h16    = (unsigned short*)take((size_t)N_NODES * F_HID * 2);  // 51.2 MB, dinv-scaled bf16
  unsigned short* wt     = (unsigned short*)take((size_t)F_HID * KP * 2);
  float*          h2s    = (float*)take((size_t)N_NODES * 2 * 4);
  int*            cnt    = (int*)take((size_t)N_NODES * 4);
  int*            fill   = (int*)take((size_t)N_NODES * 4);
  int*            rowptr = (int*)take(((size_t)N_NODES + 1) * 4);
  int*            srcl   = (int*)take(((size_t)N_EDGES + 8) * 4);  // +8 pad for speculative unroll reads
  float*          dinv   = (float*)take((size_t)N_NODES * 4);
  int*            bsum   = (int*)take(4096);
  (void)ws_size; (void)in_sizes; (void)n_in; (void)out_size;

  int nbE = (N_EDGES + 255) / 256;
  int nbN = (N_NODES + 255) / 256;
  k_zero<<<nbN, 256, 0, stream>>>(cnt);
  k_count<<<nbE, 256, 0, stream>>>(ei, cnt);
  k_scan1<<<nbN, 256, 0, stream>>>(cnt, rowptr, bsum);
  k_scan2<<<1, 1024, 0, stream>>>(bsum, nbN);
  k_scan3<<<nbN, 256, 0, stream>>>(cnt, bsum, rowptr, fill, dinv);
  k_fill<<<nbE, 256, 0, stream>>>(ei, fill, srcl);
  k_wt<<<(F_HID * KP + 255) / 256, 256, 0, stream>>>(W1, wt);
  k_gemm1<<<N_NODES / 32, 256, 0, stream>>>(x, wt, dinv, h16);
  k_agg1<<<N_NODES / 4, 256, 0, stream>>>((const unsigned int*)h16, dinv, rowptr, srcl, b1, W2, h2s);
  k_agg2<<<nbN, 256, 0, stream>>>(h2s, dinv, rowptr, srcl, b2, out);
}

// Round 4
// 184.996 us; speedup vs baseline: 1.7517x; 1.1514x over previous
//
#include <hip/hip_runtime.h>

#define N_NODES 200000
#define N_EDGES 600000
#define F_IN 165
#define F_HID 128
#define KP 200   // LDS row stride (ushorts); 400B => dword-stride 100 => banks 4c%32, ~2-way
#define NT 6250  // 200000/32 row-tiles

typedef short short8 __attribute__((ext_vector_type(8)));
typedef float f32x4 __attribute__((ext_vector_type(4)));

__device__ __forceinline__ unsigned short f2bf(float f) {
  union { float f; unsigned int u; } v; v.f = f;
  unsigned int u = v.u;
  return (unsigned short)((u + 0x7FFFu + ((u >> 16) & 1u)) >> 16);  // RNE
}
__device__ __forceinline__ float bflo(unsigned int v) {
  union { unsigned int u; float f; } x; x.u = v << 16; return x.f;
}
__device__ __forceinline__ float bfhi(unsigned int v) {
  union { unsigned int u; float f; } x; x.u = v & 0xffff0000u; return x.f;
}

// ---- zero scratch counters (graph-replayed node, not hipMemsetAsync) ----
__global__ void k_zero(int* __restrict__ cnt) {
  int i = blockIdx.x * 256 + threadIdx.x;
  if (i < N_NODES) cnt[i] = 0;
}

// ---- CSR build ----
__global__ void k_count(const int* __restrict__ ei, int* __restrict__ cnt) {
  int e = blockIdx.x * 256 + threadIdx.x;
  if (e < N_EDGES) atomicAdd(&cnt[ei[N_EDGES + e]], 1);
}

__global__ void k_scan1(const int* __restrict__ cnt, int* __restrict__ rowptr, int* __restrict__ bsum) {
  __shared__ int sd[256];
  int t = threadIdx.x;
  int idx = blockIdx.x * 256 + t;
  int v = (idx < N_NODES) ? cnt[idx] : 0;
  sd[t] = v; __syncthreads();
  #pragma unroll
  for (int off = 1; off < 256; off <<= 1) {
    int u = (t >= off) ? sd[t - off] : 0;
    __syncthreads();
    sd[t] += u;
    __syncthreads();
  }
  if (idx < N_NODES) rowptr[idx] = sd[t] - v;  // exclusive within block
  if (t == 255) bsum[blockIdx.x] = sd[t];
}

__global__ void k_scan2(int* __restrict__ bsum, int nb) {
  __shared__ int sd[1024];
  int t = threadIdx.x;
  int v = (t < nb) ? bsum[t] : 0;
  sd[t] = v; __syncthreads();
  for (int off = 1; off < 1024; off <<= 1) {
    int u = (t >= off) ? sd[t - off] : 0;
    __syncthreads();
    sd[t] += u;
    __syncthreads();
  }
  if (t < nb) bsum[t] = sd[t] - v;  // exclusive block offsets
}

__global__ void k_scan3(const int* __restrict__ cnt, const int* __restrict__ bsum,
                        int* __restrict__ rowptr, int* __restrict__ fill, float* __restrict__ dinv) {
  int idx = blockIdx.x * 256 + threadIdx.x;
  if (idx < N_NODES) {
    int rp = rowptr[idx] + bsum[blockIdx.x];
    rowptr[idx] = rp;
    fill[idx] = rp;  // mutable cursor for k_fill
    dinv[idx] = rsqrtf((float)(cnt[idx] + 1));  // deg = in-degree + self-loop >= 1
  }
  if (idx == 0) rowptr[N_NODES] = N_EDGES;
}

__global__ void k_fill(const int* __restrict__ ei, int* __restrict__ fill, int* __restrict__ srcl) {
  int e = blockIdx.x * 256 + threadIdx.x;
  if (e < N_EDGES) {
    int d = ei[N_EDGES + e];
    int s = ei[e];
    int slot = atomicAdd(&fill[d], 1);
    srcl[slot] = s;
  }
}

// ---- W1^T -> bf16, padded [128][KP], zeros beyond k=165 ----
__global__ void k_wt(const float* __restrict__ W1, unsigned short* __restrict__ wt) {
  int idx = blockIdx.x * 256 + threadIdx.x;
  if (idx < F_HID * KP) {
    int c = idx / KP, k = idx - c * KP;
    wt[idx] = (k < F_IN) ? f2bf(W1[k * F_HID + c]) : (unsigned short)0;
  }
}

// ---- GEMM1: persistent blocks; Bs staged once; tile loop with reg-split async staging ----
__global__ __launch_bounds__(256) void k_gemm1(const float* __restrict__ x,
                                               const unsigned short* __restrict__ wt,
                                               const float* __restrict__ dinv,
                                               unsigned short* __restrict__ h16) {
  __shared__ unsigned short Bs[F_HID * KP];  // 51200 B
  __shared__ unsigned short As[32 * KP];     // 12800 B  (total 64000 B)
  int tid = threadIdx.x;

  // stage W^T once per block
  const uint4* wt4 = (const uint4*)wt;
  uint4* Bs4 = (uint4*)Bs;
  #pragma unroll 4
  for (int j = tid; j < F_HID * KP / 8; j += 256) Bs4[j] = wt4[j];

  // zero the As pad region (k in [165,200)) once; per-tile staging writes only k<165
  for (int j = tid; j < 32 * (KP - F_IN); j += 256) {
    int r = j / (KP - F_IN), c = F_IN + (j - (j / (KP - F_IN)) * (KP - F_IN));
    As[r * KP + c] = 0;
  }

  int t = blockIdx.x;
  int G = gridDim.x;

  // prologue: stage first tile directly
  {
    const float4* x4 = (const float4*)(x + (long)t * 32 * F_IN);  // t*21120 B, 16B-aligned
    for (int j = tid; j < 32 * F_IN / 4; j += 256) {
      float4 v = x4[j];
      int e = 4 * j;
      #pragma unroll
      for (int u = 0; u < 4; ++u) {
        int ee = e + u;
        int r = ee / F_IN, c = ee - r * F_IN;
        As[r * KP + c] = f2bf((&v.x)[u]);
      }
    }
  }
  __syncthreads();

  int lane = tid & 63;
  int w = tid >> 6;
  int rg = w & 1;   // row group (16 rows)
  int ch = w >> 1;  // col half (64 cols)
  int arow = rg * 16 + (lane & 15);
  int kg = (lane >> 4) * 8;

  while (t < NT) {
    int tn = t + G;
    bool have = tn < NT;  // uniform across block

    // phase 1: issue next tile's global loads into registers (latency hides under MFMA)
    float4 vals[6];
    if (have) {
      const float4* x4 = (const float4*)(x + (long)tn * 32 * F_IN);
      #pragma unroll
      for (int i = 0; i < 6; ++i) {
        int j = tid + i * 256;
        if (j < 32 * F_IN / 4) vals[i] = x4[j];
      }
    }

    // phase 2: compute current tile
    f32x4 acc[4];
    #pragma unroll
    for (int i = 0; i < 4; ++i) acc[i] = (f32x4){0.f, 0.f, 0.f, 0.f};
    #pragma unroll
    for (int ks = 0; ks < 6; ++ks) {  // K padded to 192, zeros beyond 165
      short8 af = *(const short8*)(&As[arow * KP + ks * 32 + kg]);
      #pragma unroll
      for (int cb = 0; cb < 4; ++cb) {
        int col = (ch * 4 + cb) * 16 + (lane & 15);
        short8 bf = *(const short8*)(&Bs[col * KP + ks * 32 + kg]);
        acc[cb] = __builtin_amdgcn_mfma_f32_16x16x32_bf16(af, bf, acc[cb], 0, 0, 0);
      }
    }
    // C/D layout: col = lane&15, row = (lane>>4)*4 + reg; scale by dinv[row], store bf16
    long orow = (long)t * 32 + rg * 16 + (lane >> 4) * 4;
    int ocol = lane & 15;
    float dv[4];
    #pragma unroll
    for (int j = 0; j < 4; ++j) dv[j] = dinv[orow + j];
    #pragma unroll
    for (int cb = 0; cb < 4; ++cb) {
      #pragma unroll
      for (int j = 0; j < 4; ++j) {
        h16[(orow + j) * F_HID + (ch * 4 + cb) * 16 + ocol] = f2bf(acc[cb][j] * dv[j]);
      }
    }
    __syncthreads();  // all reads of As done

    // phase 3: convert + write prefetched tile into As
    if (have) {
      #pragma unroll
      for (int i = 0; i < 6; ++i) {
        int j = tid + i * 256;
        if (j < 32 * F_IN / 4) {
          int e = 4 * j;
          #pragma unroll
          for (int u = 0; u < 4; ++u) {
            int ee = e + u;
            int r = ee / F_IN, c = ee - r * F_IN;
            As[r * KP + c] = f2bf((&vals[i].x)[u]);
          }
        }
      }
    }
    __syncthreads();  // As ready for next iteration
    t = tn;
  }
}

// ---- fused: agg1 (gather, 4-wide) + bias + relu + GEMM2 (128->2) ; output pre-scaled by dinv ----
__global__ __launch_bounds__(256) void k_agg1(const unsigned int* __restrict__ H,  // bf16x2 rows, 64 uints/node
                                              const float* __restrict__ dinv,
                                              const int* __restrict__ rowptr, const int* __restrict__ srcl,
                                              const float* __restrict__ b1, const float* __restrict__ W2,
                                              float* __restrict__ h2s) {
  int tid = threadIdx.x;
  int local = tid >> 6;
  int lane = tid & 63;
  int d = blockIdx.x * 4 + local;  // grid exact: 50000*4 = 200000

  unsigned int v = H[(long)d * 64 + lane];  // self (already dinv[d]-scaled)
  float acc0 = bflo(v), acc1 = bfhi(v);
  int r0 = rowptr[d], r1 = rowptr[d + 1];
  int n = r1 - r0;
  for (int b = 0; b < n; b += 4) {
    int i0 = r0 + b;
    bool m1 = b + 1 < n, m2 = b + 2 < n, m3 = b + 3 < n;
    int s0 = srcl[i0];
    int s1 = m1 ? srcl[i0 + 1] : s0;
    int s2 = m2 ? srcl[i0 + 2] : s0;
    int s3 = m3 ? srcl[i0 + 3] : s0;
    unsigned int v0 = H[(long)s0 * 64 + lane];
    unsigned int v1 = H[(long)s1 * 64 + lane];
    unsigned int v2 = H[(long)s2 * 64 + lane];
    unsigned int v3 = H[(long)s3 * 64 + lane];
    acc0 += bflo(v0);                      acc1 += bfhi(v0);
    acc0 = fmaf(m1 ? 1.f : 0.f, bflo(v1), acc0); acc1 = fmaf(m1 ? 1.f : 0.f, bfhi(v1), acc1);
    acc0 = fmaf(m2 ? 1.f : 0.f, bflo(v2), acc0); acc1 = fmaf(m2 ? 1.f : 0.f, bfhi(v2), acc1);
    acc0 = fmaf(m3 ? 1.f : 0.f, bflo(v3), acc0); acc1 = fmaf(m3 ? 1.f : 0.f, bfhi(v3), acc1);
  }
  float dd = dinv[d];
  float2 bb = ((const float2*)b1)[lane];
  float a0 = fmaxf(fmaf(acc0, dd, bb.x), 0.f);
  float a1 = fmaxf(fmaf(acc1, dd, bb.y), 0.f);
  float4 w2 = ((const float4*)W2)[lane];  // W2[2*lane][0..1], W2[2*lane+1][0..1]
  float p0 = a0 * w2.x + a1 * w2.z;
  float p1 = a0 * w2.y + a1 * w2.w;
  #pragma unroll
  for (int off = 32; off > 0; off >>= 1) {
    p0 += __shfl_down(p0, off);
    p1 += __shfl_down(p1, off);
  }
  if (lane == 0) ((float2*)h2s)[d] = make_float2(p0 * dd, p1 * dd);
}

// ---- agg2 over 2 features + bias (h2s pre-scaled by dinv) ----
__global__ void k_agg2(const float* __restrict__ h2s, const float* __restrict__ dinv,
                       const int* __restrict__ rowptr, const int* __restrict__ srcl,
                       const float* __restrict__ b2, float* __restrict__ out) {
  int d = blockIdx.x * 256 + threadIdx.x;
  if (d >= N_NODES) return;
  const float2* G = (const float2*)h2s;
  float2 g = G[d];
  float o0 = g.x, o1 = g.y;
  int r0 = rowptr[d], r1 = rowptr[d + 1];
  int n = r1 - r0;
  for (int b = 0; b < n; b += 4) {
    int i0 = r0 + b;
    bool m1 = b + 1 < n, m2 = b + 2 < n, m3 = b + 3 < n;
    int s0 = srcl[i0];
    int s1 = m1 ? srcl[i0 + 1] : s0;
    int s2 = m2 ? srcl[i0 + 2] : s0;
    int s3 = m3 ? srcl[i0 + 3] : s0;
    float2 g0 = G[s0], g1 = G[s1], g2 = G[s2], g3 = G[s3];
    o0 += g0.x;                   o1 += g0.y;
    o0 = fmaf(m1 ? 1.f : 0.f, g1.x, o0); o1 = fmaf(m1 ? 1.f : 0.f, g1.y, o1);
    o0 = fmaf(m2 ? 1.f : 0.f, g2.x, o0); o1 = fmaf(m2 ? 1.f : 0.f, g2.y, o1);
    o0 = fmaf(m3 ? 1.f : 0.f, g3.x, o0); o1 = fmaf(m3 ? 1.f : 0.f, g3.y, o1);
  }
  float dd = dinv[d];
  ((float2*)out)[d] = make_float2(fmaf(o0, dd, b2[0]), fmaf(o1, dd, b2[1]));
}

extern "C" void kernel_launch(void* const* d_in, const int* in_sizes, int n_in,
                              void* d_out, int out_size, void* d_ws, size_t ws_size,
                              hipStream_t stream) {
  const float* x  = (const float*)d_in[0];
  const int*   ei = (const int*)d_in[1];
  const float* W1 = (const float*)d_in[2];
  const float* b1 = (const float*)d_in[3];
  const float* W2 = (const float*)d_in[4];
  const float* b2 = (const float*)d_in[5];
  float* out = (float*)d_out;

  char* p = (char*)d_ws;
  size_t off = 0;
  auto take = [&](size_t bytes) -> void* {
    void* r = p + off;
    off += (bytes + 255) & ~(size_t)255;
    return r;
  };
  unsigned short* h16    = (unsigned short*)take((size_t)N_NODES * F_HID * 2);  // 51.2 MB, dinv-scaled bf16
  unsigned short* wt     = (unsigned short*)take((size_t)F_HID * KP * 2);
  float*          h2s    = (float*)take((size_t)N_NODES * 2 * 4);
  int*            cnt    = (int*)take((size_t)N_NODES * 4);
  int*            fill   = (int*)take((size_t)N_NODES * 4);
  int*            rowptr = (int*)take(((size_t)N_NODES + 1) * 4);
  int*            srcl   = (int*)take(((size_t)N_EDGES + 8) * 4);  // +8 pad for speculative unroll reads
  float*          dinv   = (float*)take((size_t)N_NODES * 4);
  int*            bsum   = (int*)take(4096);
  (void)ws_size; (void)in_sizes; (void)n_in; (void)out_size;

  int nbE = (N_EDGES + 255) / 256;
  int nbN = (N_NODES + 255) / 256;
  k_zero<<<nbN, 256, 0, stream>>>(cnt);
  k_count<<<nbE, 256, 0, stream>>>(ei, cnt);
  k_scan1<<<nbN, 256, 0, stream>>>(cnt, rowptr, bsum);
  k_scan2<<<1, 1024, 0, stream>>>(bsum, nbN);
  k_scan3<<<nbN, 256, 0, stream>>>(cnt, bsum, rowptr, fill, dinv);
  k_fill<<<nbE, 256, 0, stream>>>(ei, fill, srcl);
  k_wt<<<(F_HID * KP + 255) / 256, 256, 0, stream>>>(W1, wt);
  k_gemm1<<<512, 256, 0, stream>>>(x, wt, dinv, h16);  // persistent: 2 blocks/CU co-resident
  k_agg1<<<N_NODES / 4, 256, 0, stream>>>((const unsigned int*)h16, dinv, rowptr, srcl, b1, W2, h2s);
  k_agg2<<<nbN, 256, 0, stream>>>(h2s, dinv, rowptr, srcl, b2, out);
}